// Round 7
// baseline (1141.988 us; speedup 1.0000x reference)
//
#include <hip/hip_runtime.h>
#include <hip/hip_bf16.h>

// Diffusion decoder, algebraically factored:
//   cond_b = MLP(pe[t_b]);  q_b = Wq@(qe_b+cond_b);  qk_b = q_b @ Wk
//   logit[b,v] = qk_b . te[b,v] + qk_b.cond_b + x[b,v]       (fp32 pass over te)
//   w = softmax(logit); s_b = sum_v w te[b,v]                (bf16 pass over te)
//   new_emb_b = Wp@(Wv@(s_b+cond_b)) + bp
//   A_b = Wd1[:, :512]@new_emb_b + bd1
//   p[b,v] = Wd2 . relu(A_b + Wd1[:,512:]@te[b,v]) + bd2 + w (bf16 MFMA GEMM, fused epilogue)
//
// v7 decoder: v5/v6 both spilled (acc tile > VGPR budget). Wave tile now 64x64
// (acc=64 VGPR, total ~190 < 256). Block = 128 rows x 1024 cols in 4 passes.
// A (te16) in LDS once (128 KB, XOR swizzle, read-only). B global->reg dbuf,
// wave-private coalesced 4KB groups. pacc accumulates across passes -> no
// barriers in the main loop; single cross-wave reduce at the end.

typedef __attribute__((ext_vector_type(8))) short bhalf8_t;   // 8 bf16 in 4 VGPRs
typedef __attribute__((ext_vector_type(8))) unsigned short ushort8_t;
typedef __attribute__((ext_vector_type(4))) float fx4_t;

__device__ __forceinline__ unsigned short f2bf(float f) {
  unsigned int u = __float_as_uint(f);
  unsigned int r = (u + 0x7FFFu + ((u >> 16) & 1u)) >> 16;  // RNE
  return (unsigned short)r;
}
__device__ __forceinline__ float bf2f(unsigned short h) {
  return __uint_as_float((unsigned int)h << 16);
}

__device__ __forceinline__ float wave_sum64(float s) {
#pragma unroll
  for (int o = 32; o; o >>= 1) s += __shfl_xor(s, o, 64);
  return s;
}

// ---------------- T: five 512x512 transposes in one launch ----------------
__global__ __launch_bounds__(256) void transpose5_kernel(
    const float* __restrict__ s0, const float* __restrict__ s1, const float* __restrict__ s2,
    const float* __restrict__ s3, const float* __restrict__ s4,
    float* __restrict__ d0, float* __restrict__ d1, float* __restrict__ d2,
    float* __restrict__ d3, float* __restrict__ d4) {
  __shared__ float t[32][33];
  const float* src; float* dst;
  switch (blockIdx.z) {
    case 0: src = s0; dst = d0; break;
    case 1: src = s1; dst = d1; break;
    case 2: src = s2; dst = d2; break;
    case 3: src = s3; dst = d3; break;
    default: src = s4; dst = d4; break;
  }
  const int tx = threadIdx.x & 31, ty = threadIdx.x >> 5;
  const int c0 = blockIdx.x * 32, r0 = blockIdx.y * 32;
#pragma unroll
  for (int i = 0; i < 32; i += 8)
    t[ty + i][tx] = src[(size_t)(r0 + ty + i) * 512 + c0 + tx];
  __syncthreads();
#pragma unroll
  for (int i = 0; i < 32; i += 8)
    dst[(size_t)(c0 + ty + i) * 512 + r0 + tx] = t[tx][ty + i];
}

// ---------------- T': transpose Wd1[:, :512] (1024 rows) -> Wd1aT [512][1024] ----------------
__global__ __launch_bounds__(256) void transposed1_kernel(const float* __restrict__ src,
                                                          float* __restrict__ dst) {
  __shared__ float t[32][33];
  const int tx = threadIdx.x & 31, ty = threadIdx.x >> 5;
  const int c0 = blockIdx.x * 32, r0 = blockIdx.y * 32;
#pragma unroll
  for (int i = 0; i < 32; i += 8)
    t[ty + i][tx] = src[(size_t)(r0 + ty + i) * 1024 + c0 + tx];
  __syncthreads();
#pragma unroll
  for (int i = 0; i < 32; i += 8)
    dst[(size_t)(c0 + ty + i) * 1024 + r0 + tx] = t[tx][ty + i];
}

// ---------------- G: batched mat-vec  out[b][j] = act(bias[j] + sum_k arow[b][k] * WT[k][j]) ----------------
// MODE: 0 = arow from sinusoidal PE of timesteps[b]; 1 = src1[b]; 2 = src1[b]+src2[b];
//       3 = src2[b] + sum_{q<8} src1[(b*8+q)*512]
// DOT: also accumulate dot(out_row, src2[b]) into dotout[b] (for constb)
template <int MODE, int ACT, int DOT>
__global__ __launch_bounds__(256) void gvec_kernel(
    const float* __restrict__ WT, int n, const float* __restrict__ src1,
    const float* __restrict__ src2, const float* __restrict__ bias,
    const int* __restrict__ timesteps, float* __restrict__ outp,
    float* __restrict__ dotout) {
  __shared__ __attribute__((aligned(16))) float arow[512];
  const int b = blockIdx.x, tid = threadIdx.x;
  if (MODE == 0) {
    const int ts = timesteps[b];
    const float NEG = -9.2103403719761836f / 512.f;  // -ln(10000)/512
    float dv = expf((float)(2 * tid) * NEG);
    float ang = (float)ts * dv;
    arow[2 * tid] = sinf(ang);
    arow[2 * tid + 1] = cosf(ang);
  } else {
#pragma unroll
    for (int k = tid; k < 512; k += 256) {
      float a;
      if (MODE == 1) {
        a = src1[(size_t)b * 512 + k];
      } else if (MODE == 2) {
        a = src1[(size_t)b * 512 + k] + src2[(size_t)b * 512 + k];
      } else {
        a = src2[(size_t)b * 512 + k];
#pragma unroll
        for (int q = 0; q < 8; ++q) a += src1[((size_t)b * 8 + q) * 512 + k];
      }
      arow[k] = a;
    }
  }
  __syncthreads();
  const int j = blockIdx.y * 256 + tid;
  const float* w = WT + j;
  float s0 = 0.f, s1 = 0.f, s2 = 0.f, s3 = 0.f;
#pragma unroll 4
  for (int k = 0; k < 512; k += 4) {
    s0 = fmaf(arow[k], w[(size_t)k * n], s0);
    s1 = fmaf(arow[k + 1], w[(size_t)(k + 1) * n], s1);
    s2 = fmaf(arow[k + 2], w[(size_t)(k + 2) * n], s2);
    s3 = fmaf(arow[k + 3], w[(size_t)(k + 3) * n], s3);
  }
  float s = (s0 + s1) + (s2 + s3);
  if (bias) s += bias[j];
  if (ACT == 1) s = s / (1.f + expf(-s));
  outp[(size_t)b * n + j] = s;
  if (DOT) {
    float p = s * src2[(size_t)b * 512 + j];
    p = wave_sum64(p);
    __shared__ float rd[4];
    if ((tid & 63) == 0) rd[tid >> 6] = p;
    __syncthreads();
    if (tid == 0) atomicAdd(dotout + b, rd[0] + rd[1] + rd[2] + rd[3]);
  }
}

// ---------------- K2: Wd1[:,512:] -> bf16, fragment-major for v7 decoder ----------------
// byte addr g*16, g = lane | n<<6 | ks<<8 | p<<12 | nh<<14
// holds W[j][512+k..+8], j = p*256 + nh*64 + n*16 + (lane&15), k = ks*32 + (lane>>4)*8
__global__ __launch_bounds__(256) void convw_kernel(const float* __restrict__ Wd1,
                                                    unsigned short* __restrict__ wsW) {
  const int g = blockIdx.x * 256 + threadIdx.x;  // 0..65535
  const int lane = g & 63;
  const int n = (g >> 6) & 3;
  const int ks = (g >> 8) & 15;
  const int p = (g >> 12) & 3;
  const int nh = (g >> 14) & 3;
  const int j = p * 256 + nh * 64 + n * 16 + (lane & 15);
  const int k = ks * 32 + (lane >> 4) * 8;
  const float* src = Wd1 + (size_t)j * 1024 + 512 + k;
  float4 f0 = *(const float4*)src;
  float4 f1 = *(const float4*)(src + 4);
  ushort4 h0 = make_ushort4(f2bf(f0.x), f2bf(f0.y), f2bf(f0.z), f2bf(f0.w));
  ushort4 h1 = make_ushort4(f2bf(f1.x), f2bf(f1.y), f2bf(f1.z), f2bf(f1.w));
  ushort4* dst = (ushort4*)((char*)wsW + (size_t)g * 16);
  dst[0] = h0;
  dst[1] = h1;
}

// ---------------- K3: logits (fp32 dot pass over te; optional bf16 te emit) ----------------
__global__ __launch_bounds__(256) void logits_kernel(
    const float* __restrict__ te, const float* __restrict__ qk,
    const float* __restrict__ constb, const float* __restrict__ x,
    float* __restrict__ logits, unsigned short* __restrict__ te16, int w16) {
  const int wave = threadIdx.x >> 6, lane = threadIdx.x & 63;
  const size_t r = (size_t)blockIdx.x * 4 + wave;
  const int b = (int)(r >> 10);
  const float4* t4 = (const float4*)(te + r * 512);
  const float4* q4 = (const float4*)(qk + (size_t)b * 512);
  float4 a0 = t4[lane], a1 = t4[lane + 64];
  float4 c0 = q4[lane], c1 = q4[lane + 64];
  float s = a0.x * c0.x + a0.y * c0.y + a0.z * c0.z + a0.w * c0.w +
            a1.x * c1.x + a1.y * c1.y + a1.z * c1.z + a1.w * c1.w;
  s = wave_sum64(s);
  if (w16) {
    ushort4 h0 = make_ushort4(f2bf(a0.x), f2bf(a0.y), f2bf(a0.z), f2bf(a0.w));
    ushort4 h1 = make_ushort4(f2bf(a1.x), f2bf(a1.y), f2bf(a1.z), f2bf(a1.w));
    *(ushort4*)(te16 + r * 512 + lane * 4) = h0;
    *(ushort4*)(te16 + r * 512 + 256 + lane * 4) = h1;
  }
  if (lane == 0) logits[r] = s + constb[b] + x[r];
}

// ---------------- K4: softmax per batch; also init out = w + bd2 ----------------
__global__ __launch_bounds__(256) void softmax_kernel(
    const float* __restrict__ logits, const float* __restrict__ bd2,
    float* __restrict__ weight, float* __restrict__ out) {
  __shared__ float sm[4];
  const int b = blockIdx.x, tid = threadIdx.x;
  const int wave = tid >> 6, lane = tid & 63;
  float4 l4 = ((const float4*)(logits + (size_t)b * 1024))[tid];
  float m = fmaxf(fmaxf(l4.x, l4.y), fmaxf(l4.z, l4.w));
#pragma unroll
  for (int o = 32; o; o >>= 1) m = fmaxf(m, __shfl_xor(m, o, 64));
  if (lane == 0) sm[wave] = m;
  __syncthreads();
  float M = fmaxf(fmaxf(sm[0], sm[1]), fmaxf(sm[2], sm[3]));
  __syncthreads();
  float e0 = expf(l4.x - M), e1 = expf(l4.y - M), e2 = expf(l4.z - M), e3 = expf(l4.w - M);
  float ssum = wave_sum64(e0 + e1 + e2 + e3);
  if (lane == 0) sm[wave] = ssum;
  __syncthreads();
  float inv = 1.f / (sm[0] + sm[1] + sm[2] + sm[3]);
  float c = bd2[0];
  float4 w4 = make_float4(e0 * inv, e1 * inv, e2 * inv, e3 * inv);
  ((float4*)(weight + (size_t)b * 1024))[tid] = w4;
  ((float4*)(out + (size_t)b * 1024))[tid] = make_float4(w4.x + c, w4.y + c, w4.z + c, w4.w + c);
}

// ---------------- K5a: spart[(b,vq)][d] = sum_{v in chunk} w * te  (fp32 input) ----------------
__global__ __launch_bounds__(256) void wsum32_kernel(const float* __restrict__ te,
                                                     const float* __restrict__ weight,
                                                     float* __restrict__ spart) {
  __shared__ float wl[128];
  const int b = blockIdx.x >> 3, vq = blockIdx.x & 7;
  const int tid = threadIdx.x;
  if (tid < 128) wl[tid] = weight[(size_t)b * 1024 + vq * 128 + tid];
  __syncthreads();
  const float* tb = te + ((size_t)b * 1024 + (size_t)vq * 128) * 512;
  float s0 = 0.f, s1 = 0.f;
#pragma unroll 4
  for (int v = 0; v < 128; ++v) {
    float w = wl[v];
    s0 += w * tb[(size_t)v * 512 + tid];
    s1 += w * tb[(size_t)v * 512 + 256 + tid];
  }
  spart[(size_t)blockIdx.x * 512 + tid] = s0;
  spart[(size_t)blockIdx.x * 512 + 256 + tid] = s1;
}

// ---------------- K5a': same from bf16 te ----------------
__global__ __launch_bounds__(256) void wsum16_kernel(const unsigned short* __restrict__ te16,
                                                     const float* __restrict__ weight,
                                                     float* __restrict__ spart) {
  __shared__ float wl[128];
  __shared__ float red[4][512];
  const int b = blockIdx.x >> 3, vq = blockIdx.x & 7;
  const int tid = threadIdx.x;
  if (tid < 128) wl[tid] = weight[(size_t)b * 1024 + vq * 128 + tid];
  __syncthreads();
  const int g = tid & 63, vh = tid >> 6;
  const unsigned short* base =
      te16 + ((size_t)b * 1024 + vq * 128 + vh * 32) * 512 + g * 8;
  float acc[8] = {};
  for (int v = 0; v < 32; ++v) {
    float w = wl[vh * 32 + v];
    ushort8_t h = *(const ushort8_t*)(base + (size_t)v * 512);
#pragma unroll
    for (int i = 0; i < 8; ++i) acc[i] += w * bf2f(h[i]);
  }
#pragma unroll
  for (int i = 0; i < 8; ++i) red[vh][g * 8 + i] = acc[i];
  __syncthreads();
  for (int d = tid; d < 512; d += 256)
    spart[(size_t)blockIdx.x * 512 + d] =
        red[0][d] + red[1][d] + red[2][d] + red[3][d];
}

// ---------------- K6: decoder GEMM + fused epilogue (v7) ----------------
// 1024 blocks x 512 thr (8 waves = 2mh x 4nh). Block: 128 rows x 1024 cols
// in 4 passes of 256 cols. Wave tile 64 rows x 64 cols: acc 4x4 fx4 = 64 VGPR.
// A (te16) in LDS once (128 KB, XOR swizzle). B global->reg, dbuf'd 4KB groups.
// pacc accumulates across passes; NO barriers in the main loop.
#define GLD16(g, l)                                                              \
  __builtin_amdgcn_global_load_lds((const __attribute__((address_space(1))) void*)(g), \
                                   (__attribute__((address_space(3))) void*)(l), 16, 0, 0)

template <int USE16>
__global__ __launch_bounds__(512, 2) void decoder_kernel(
    const float* __restrict__ te, const unsigned short* __restrict__ te16,
    const unsigned short* __restrict__ wsW, const float* __restrict__ A,
    const float* __restrict__ Wd2, float* __restrict__ out) {
  extern __shared__ char lds[];             // A 131072 | av 4096 | wv 4096 | red 2048
  float* av_lds = (float*)(lds + 131072);
  float* wv_lds = (float*)(lds + 135168);
  float* red = (float*)(lds + 139264);

  const int tid = threadIdx.x;
  const int wave = tid >> 6, lane = tid & 63;
  const int lhi = lane >> 4, llo = lane & 15;
  const int mh = wave >> 2, nh = wave & 3;
  const size_t r0 = (size_t)blockIdx.x * 128;
  const int b = (int)(blockIdx.x >> 3);

  // ---- stage A (128 rows x 1KB bf16) into LDS, byte ^= (row&7)<<4 swizzle ----
  if (USE16) {
    const char* src = (const char*)te16 + r0 * 1024;
#pragma unroll
    for (int it = 0; it < 16; ++it) {
      const int r = it * 8 + wave;  // r&7 == wave
      GLD16(src + (size_t)r * 1024 + ((lane * 16) ^ (wave << 4)), lds + r * 1024);
    }
  } else {
    const float* src = te + r0 * 512;
#pragma unroll
    for (int it = 0; it < 16; ++it) {
      int u = it * 512 + tid;  // 8192 16B-units
      int r = u >> 6, c = u & 63;
      const float4* s = (const float4*)(src + (size_t)r * 512 + c * 8);
      float4 f0 = s[0], f1 = s[1];
      ushort4 h0 = make_ushort4(f2bf(f0.x), f2bf(f0.y), f2bf(f0.z), f2bf(f0.w));
      ushort4 h1 = make_ushort4(f2bf(f1.x), f2bf(f1.y), f2bf(f1.z), f2bf(f1.w));
      char* d = lds + r * 1024 + ((c * 16) ^ ((r & 7) << 4));
      *(ushort4*)d = h0;
      *(ushort4*)(d + 8) = h1;
    }
  }
  // ---- stage av/wv (this block's batch row of A, and Wd2) ----
  {
    const float* A_g = A + (size_t)b * 1024;
    av_lds[tid] = A_g[tid];        av_lds[tid + 512] = A_g[tid + 512];
    wv_lds[tid] = Wd2[tid];        wv_lds[tid + 512] = Wd2[tid + 512];
  }
  asm volatile("s_waitcnt vmcnt(0)" ::: "memory");
  __syncthreads();

  // ---- main loop ----
  const int xr = (llo & 7) << 4;
  const char* abase = lds + mh * 65536 + llo * 1024;           // + m*16384 + off
  const char* wb = (const char*)wsW + ((size_t)nh << 18) + lane * 16;  // + g<<12 + n*1024

  fx4_t acc[4][4];
  float pacc[4][4] = {};
  const fx4_t zf = {0.f, 0.f, 0.f, 0.f};
  bhalf8_t bw0[4], bw1[4];

  auto issue = [&](bhalf8_t (&dst)[4], int g) {
    const char* p_ = wb + ((size_t)g << 12);
#pragma unroll
    for (int n = 0; n < 4; ++n) dst[n] = *(const bhalf8_t*)(p_ + n * 1024);
  };
  auto body = [&](bhalf8_t (&bw)[4], int ks) {
    const int off = (ks * 64 + lhi * 16) ^ xr;
    bhalf8_t a0 = *(const bhalf8_t*)(abase + off);
    bhalf8_t a1 = *(const bhalf8_t*)(abase + 16384 + off);
    bhalf8_t a2 = *(const bhalf8_t*)(abase + 32768 + off);
    bhalf8_t a3 = *(const bhalf8_t*)(abase + 49152 + off);
#pragma unroll
    for (int n = 0; n < 4; ++n) {
      acc[0][n] = __builtin_amdgcn_mfma_f32_16x16x32_bf16(a0, bw[n], acc[0][n], 0, 0, 0);
      acc[1][n] = __builtin_amdgcn_mfma_f32_16x16x32_bf16(a1, bw[n], acc[1][n], 0, 0, 0);
      acc[2][n] = __builtin_amdgcn_mfma_f32_16x16x32_bf16(a2, bw[n], acc[2][n], 0, 0, 0);
      acc[3][n] = __builtin_amdgcn_mfma_f32_16x16x32_bf16(a3, bw[n], acc[3][n], 0, 0, 0);
    }
  };

  issue(bw0, 0);
  issue(bw1, 1);
#pragma unroll
  for (int p = 0; p < 4; ++p) {
#pragma unroll
    for (int m = 0; m < 4; ++m)
#pragma unroll
      for (int n = 0; n < 4; ++n) acc[m][n] = zf;
#pragma unroll
    for (int kp = 0; kp < 8; ++kp) {
      const int g = p * 16 + kp * 2;
      body(bw0, kp * 2);
      if (g + 2 <= 63) issue(bw0, g + 2);
      body(bw1, kp * 2 + 1);
      if (g + 3 <= 63) issue(bw1, g + 3);
    }
    // ---- epilogue for this 256-col pass (LDS scalars only; pacc in regs) ----
#pragma unroll
    for (int n = 0; n < 4; ++n) {
      const int j = p * 256 + nh * 64 + n * 16 + llo;
      const float av = av_lds[j];
      const float wvv = wv_lds[j];
#pragma unroll
      for (int m = 0; m < 4; ++m)
#pragma unroll
        for (int rg = 0; rg < 4; ++rg)
          pacc[m][rg] += fmaxf(acc[m][n][rg] + av, 0.f) * wvv;
    }
  }

  // ---- cross-lane + cross-wave reduction ----
#pragma unroll
  for (int m = 0; m < 4; ++m)
#pragma unroll
    for (int rg = 0; rg < 4; ++rg) {
      float sv = pacc[m][rg];
      sv += __shfl_xor(sv, 1, 64);
      sv += __shfl_xor(sv, 2, 64);
      sv += __shfl_xor(sv, 4, 64);
      sv += __shfl_xor(sv, 8, 64);
      if (llo == 0) red[wave * 64 + m * 16 + lhi * 4 + rg] = sv;
    }
  __syncthreads();
  if (tid < 128) {
    const int mh2 = tid >> 6, rl = tid & 63;
    float s = red[(mh2 * 4 + 0) * 64 + rl] + red[(mh2 * 4 + 1) * 64 + rl] +
              red[(mh2 * 4 + 2) * 64 + rl] + red[(mh2 * 4 + 3) * 64 + rl];
    out[r0 + tid] += s;  // out pre-initialized to w + bd2; rows exclusive per block
  }
}

// ---------------- launch ----------------
extern "C" void kernel_launch(void* const* d_in, const int* in_sizes, int n_in,
                              void* d_out, int out_size, void* d_ws, size_t ws_size,
                              hipStream_t stream) {
  const float* x = (const float*)d_in[0];
  const int* tsteps = (const int*)d_in[1];
  const float* qe = (const float*)d_in[2];
  const float* te = (const float*)d_in[3];
  const float* Wq = (const float*)d_in[4];
  const float* Wk = (const float*)d_in[5];
  const float* Wv = (const float*)d_in[6];
  const float* Wp = (const float*)d_in[7];
  const float* bp = (const float*)d_in[8];
  const float* Wt1 = (const float*)d_in[9];
  const float* bt1 = (const float*)d_in[10];
  const float* Wt2 = (const float*)d_in[11];
  const float* bt2 = (const float*)d_in[12];
  const float* Wd1 = (const float*)d_in[13];
  const float* bd1 = (const float*)d_in[14];
  const float* Wd2 = (const float*)d_in[15];
  const float* bd2 = (const float*)d_in[16];
  float* out = (float*)d_out;

  char* ws = (char*)d_ws;
  unsigned short* wsW = (unsigned short*)(ws + 0);     // 1 MB
  float* Wt1T = (float*)(ws + 1048576);                // 1 MB each
  float* Wt2T = (float*)(ws + 2097152);
  float* WqT = (float*)(ws + 3145728);
  float* WvT = (float*)(ws + 4194304);
  float* WpT = (float*)(ws + 5242880);
  float* Wd1aT = (float*)(ws + 6291456);               // 2 MB [512][1024]
  float* cond = (float*)(ws + 8388608);                // 256 KB each
  float* qk = (float*)(ws + 8650752);
  float* hbuf = (float*)(ws + 8912896);
  float* qbuf = (float*)(ws + 9175040);
  float* ubuf = (float*)(ws + 9437184);
  float* nebuf = (float*)(ws + 9699328);
  float* cb = (float*)(ws + 9961472);                  // 4 KB slot
  float* logits = (float*)(ws + 9965568);              // 512 KB
  float* wgt = (float*)(ws + 10489856);                // 512 KB
  float* spart = (float*)(ws + 11014144);              // 2 MB [128*8][512]
  float* Abuf = (float*)(ws + 13111296);               // 512 KB
  const size_t TE16_OFF = 14680064;                    // 14 MB
  const size_t TE16_BYTES = (size_t)128 * 1024 * 512 * 2;  // 128 MB
  unsigned short* te16 = (unsigned short*)(ws + TE16_OFF);
  const int use16 = (ws_size >= TE16_OFF + TE16_BYTES) ? 1 : 0;

  // weight transposes (coalesced mat-vec reads) + decoder W pre-pack
  transpose5_kernel<<<dim3(16, 16, 5), 256, 0, stream>>>(Wt1, Wt2, Wq, Wv, Wp,
                                                         Wt1T, Wt2T, WqT, WvT, WpT);
  transposed1_kernel<<<dim3(16, 32), 256, 0, stream>>>(Wd1, Wd1aT);
  convw_kernel<<<256, 256, 0, stream>>>(Wd1, wsW);

  // cond / q / qk chain (batched mat-vecs); constb fused into the qk pass
  hipMemsetAsync(cb, 0, 128 * sizeof(float), stream);
  gvec_kernel<0, 1, 0><<<dim3(128, 2), 256, 0, stream>>>(Wt1T, 512, nullptr, nullptr, bt1, tsteps, hbuf, nullptr);
  gvec_kernel<1, 0, 0><<<dim3(128, 2), 256, 0, stream>>>(Wt2T, 512, hbuf, nullptr, bt2, nullptr, cond, nullptr);
  gvec_kernel<2, 0, 0><<<dim3(128, 2), 256, 0, stream>>>(WqT, 512, qe, cond, nullptr, nullptr, qbuf, nullptr);
  gvec_kernel<1, 0, 1><<<dim3(128, 2), 256, 0, stream>>>(Wk, 512, qbuf, cond, nullptr, nullptr, qk, cb);

  logits_kernel<<<32768, 256, 0, stream>>>(te, qk, cb, x, logits, te16, use16);
  softmax_kernel<<<128, 256, 0, stream>>>(logits, bd2, wgt, out);
  if (use16)
    wsum16_kernel<<<1024, 256, 0, stream>>>(te16, wgt, spart);
  else
    wsum32_kernel<<<1024, 256, 0, stream>>>(te, wgt, spart);

  // new_emb -> A chain
  gvec_kernel<3, 0, 0><<<dim3(128, 2), 256, 0, stream>>>(WvT, 512, spart, cond, nullptr, nullptr, ubuf, nullptr);
  gvec_kernel<1, 0, 0><<<dim3(128, 2), 256, 0, stream>>>(WpT, 512, ubuf, nullptr, bp, nullptr, nebuf, nullptr);
  gvec_kernel<1, 0, 0><<<dim3(128, 4), 256, 0, stream>>>(Wd1aT, 1024, nebuf, nullptr, bd1, nullptr, Abuf, nullptr);

  if (use16) {
    (void)hipFuncSetAttribute((const void*)decoder_kernel<1>,
                              hipFuncAttributeMaxDynamicSharedMemorySize, 141312);
    decoder_kernel<1><<<1024, 512, 141312, stream>>>(te, te16, wsW, Abuf, Wd2, out);
  } else {
    (void)hipFuncSetAttribute((const void*)decoder_kernel<0>,
                              hipFuncAttributeMaxDynamicSharedMemorySize, 141312);
    decoder_kernel<0><<<1024, 512, 141312, stream>>>(te, te16, wsW, Abuf, Wd2, out);
  }
}

// Round 8
// 410.513 us; speedup vs baseline: 2.7819x; 2.7819x over previous
//
#include <hip/hip_runtime.h>
#include <hip/hip_bf16.h>

// Diffusion decoder, algebraically factored:
//   cond_b = MLP(pe[t_b]);  q_b = Wq@(qe_b+cond_b);  qk_b = q_b @ Wk
//   logit[b,v] = qk_b . te[b,v] + qk_b.cond_b + x[b,v]       (fp32 pass over te)
//   w = softmax(logit); s_b = sum_v w te[b,v]                (bf16 pass over te)
//   new_emb_b = Wp@(Wv@(s_b+cond_b)) + bp
//   A_b = Wd1[:, :512]@new_emb_b + bd1
//   p[b,v] = Wd2 . relu(A_b + Wd1[:,512:]@te[b,v]) + bd2 + w (bf16 MFMA GEMM, fused epilogue)
//
// v8 decoder: arch-VGPR budget with MFMA is ~128 (unified file splits 128 arch +
// 128 acc) — v5/v6/v7 all spilled by exceeding it. v8 = v3's A-in-LDS (te16 64KB,
// XOR-swizzled, staged via global_load_lds) + v4's W-LDS ring (4x16KB, counted
// vmcnt depth-3, shared by all 8 waves -> W L2 traffic 2GB, no duplication).
// Per-wave live regs (excl. acc): ~70 << 128. No spill by construction.

typedef __attribute__((ext_vector_type(8))) short bhalf8_t;   // 8 bf16 in 4 VGPRs
typedef __attribute__((ext_vector_type(8))) unsigned short ushort8_t;
typedef __attribute__((ext_vector_type(4))) float fx4_t;

__device__ __forceinline__ unsigned short f2bf(float f) {
  unsigned int u = __float_as_uint(f);
  unsigned int r = (u + 0x7FFFu + ((u >> 16) & 1u)) >> 16;  // RNE
  return (unsigned short)r;
}
__device__ __forceinline__ float bf2f(unsigned short h) {
  return __uint_as_float((unsigned int)h << 16);
}

__device__ __forceinline__ float wave_sum64(float s) {
#pragma unroll
  for (int o = 32; o; o >>= 1) s += __shfl_xor(s, o, 64);
  return s;
}

// ---------------- T: five 512x512 transposes in one launch ----------------
__global__ __launch_bounds__(256) void transpose5_kernel(
    const float* __restrict__ s0, const float* __restrict__ s1, const float* __restrict__ s2,
    const float* __restrict__ s3, const float* __restrict__ s4,
    float* __restrict__ d0, float* __restrict__ d1, float* __restrict__ d2,
    float* __restrict__ d3, float* __restrict__ d4) {
  __shared__ float t[32][33];
  const float* src; float* dst;
  switch (blockIdx.z) {
    case 0: src = s0; dst = d0; break;
    case 1: src = s1; dst = d1; break;
    case 2: src = s2; dst = d2; break;
    case 3: src = s3; dst = d3; break;
    default: src = s4; dst = d4; break;
  }
  const int tx = threadIdx.x & 31, ty = threadIdx.x >> 5;
  const int c0 = blockIdx.x * 32, r0 = blockIdx.y * 32;
#pragma unroll
  for (int i = 0; i < 32; i += 8)
    t[ty + i][tx] = src[(size_t)(r0 + ty + i) * 512 + c0 + tx];
  __syncthreads();
#pragma unroll
  for (int i = 0; i < 32; i += 8)
    dst[(size_t)(c0 + ty + i) * 512 + r0 + tx] = t[tx][ty + i];
}

// ---------------- T': transpose Wd1[:, :512] (1024 rows) -> Wd1aT [512][1024] ----------------
__global__ __launch_bounds__(256) void transposed1_kernel(const float* __restrict__ src,
                                                          float* __restrict__ dst) {
  __shared__ float t[32][33];
  const int tx = threadIdx.x & 31, ty = threadIdx.x >> 5;
  const int c0 = blockIdx.x * 32, r0 = blockIdx.y * 32;
#pragma unroll
  for (int i = 0; i < 32; i += 8)
    t[ty + i][tx] = src[(size_t)(r0 + ty + i) * 1024 + c0 + tx];
  __syncthreads();
#pragma unroll
  for (int i = 0; i < 32; i += 8)
    dst[(size_t)(c0 + ty + i) * 1024 + r0 + tx] = t[tx][ty + i];
}

// ---------------- G: batched mat-vec  out[b][j] = act(bias[j] + sum_k arow[b][k] * WT[k][j]) ----------------
// MODE: 0 = arow from sinusoidal PE of timesteps[b]; 1 = src1[b]; 2 = src1[b]+src2[b];
//       3 = src2[b] + sum_{q<8} src1[(b*8+q)*512]
// DOT: also accumulate dot(out_row, src2[b]) into dotout[b] (for constb)
template <int MODE, int ACT, int DOT>
__global__ __launch_bounds__(256) void gvec_kernel(
    const float* __restrict__ WT, int n, const float* __restrict__ src1,
    const float* __restrict__ src2, const float* __restrict__ bias,
    const int* __restrict__ timesteps, float* __restrict__ outp,
    float* __restrict__ dotout) {
  __shared__ __attribute__((aligned(16))) float arow[512];
  const int b = blockIdx.x, tid = threadIdx.x;
  if (MODE == 0) {
    const int ts = timesteps[b];
    const float NEG = -9.2103403719761836f / 512.f;  // -ln(10000)/512
    float dv = expf((float)(2 * tid) * NEG);
    float ang = (float)ts * dv;
    arow[2 * tid] = sinf(ang);
    arow[2 * tid + 1] = cosf(ang);
  } else {
#pragma unroll
    for (int k = tid; k < 512; k += 256) {
      float a;
      if (MODE == 1) {
        a = src1[(size_t)b * 512 + k];
      } else if (MODE == 2) {
        a = src1[(size_t)b * 512 + k] + src2[(size_t)b * 512 + k];
      } else {
        a = src2[(size_t)b * 512 + k];
#pragma unroll
        for (int q = 0; q < 8; ++q) a += src1[((size_t)b * 8 + q) * 512 + k];
      }
      arow[k] = a;
    }
  }
  __syncthreads();
  const int j = blockIdx.y * 256 + tid;
  const float* w = WT + j;
  float s0 = 0.f, s1 = 0.f, s2 = 0.f, s3 = 0.f;
#pragma unroll 4
  for (int k = 0; k < 512; k += 4) {
    s0 = fmaf(arow[k], w[(size_t)k * n], s0);
    s1 = fmaf(arow[k + 1], w[(size_t)(k + 1) * n], s1);
    s2 = fmaf(arow[k + 2], w[(size_t)(k + 2) * n], s2);
    s3 = fmaf(arow[k + 3], w[(size_t)(k + 3) * n], s3);
  }
  float s = (s0 + s1) + (s2 + s3);
  if (bias) s += bias[j];
  if (ACT == 1) s = s / (1.f + expf(-s));
  outp[(size_t)b * n + j] = s;
  if (DOT) {
    float p = s * src2[(size_t)b * 512 + j];
    p = wave_sum64(p);
    __shared__ float rd[4];
    if ((tid & 63) == 0) rd[tid >> 6] = p;
    __syncthreads();
    if (tid == 0) atomicAdd(dotout + b, rd[0] + rd[1] + rd[2] + rd[3]);
  }
}

// ---------------- K2: Wd1[:,512:] -> bf16 in fragment-major 16KB chunks ----------------
// byte addr g*16, g = lane | kc<<6 | (nh*2+n)<<7 | ks<<10 | nc<<13
// holds W[j][512+k..+8], j = nc*128 + nh*32 + n*16 + (lane&15), k = ks*64 + kc*32 + (lane>>4)*8
__global__ __launch_bounds__(256) void convw_kernel(const float* __restrict__ Wd1,
                                                    unsigned short* __restrict__ wsW) {
  const int g = blockIdx.x * 256 + threadIdx.x;  // 0..65535
  const int lane = g & 63;
  const int kc = (g >> 6) & 1;
  const int nhn = (g >> 7) & 7;
  const int ks = (g >> 10) & 7;
  const int nc = g >> 13;
  const int j = nc * 128 + (nhn >> 1) * 32 + (nhn & 1) * 16 + (lane & 15);
  const int k = ks * 64 + kc * 32 + (lane >> 4) * 8;
  const float* src = Wd1 + (size_t)j * 1024 + 512 + k;
  float4 f0 = *(const float4*)src;
  float4 f1 = *(const float4*)(src + 4);
  ushort4 h0 = make_ushort4(f2bf(f0.x), f2bf(f0.y), f2bf(f0.z), f2bf(f0.w));
  ushort4 h1 = make_ushort4(f2bf(f1.x), f2bf(f1.y), f2bf(f1.z), f2bf(f1.w));
  ushort4* dst = (ushort4*)((char*)wsW + (size_t)g * 16);
  dst[0] = h0;
  dst[1] = h1;
}

// ---------------- K3: logits (fp32 dot pass over te; optional bf16 te emit) ----------------
__global__ __launch_bounds__(256) void logits_kernel(
    const float* __restrict__ te, const float* __restrict__ qk,
    const float* __restrict__ constb, const float* __restrict__ x,
    float* __restrict__ logits, unsigned short* __restrict__ te16, int w16) {
  const int wave = threadIdx.x >> 6, lane = threadIdx.x & 63;
  const size_t r = (size_t)blockIdx.x * 4 + wave;
  const int b = (int)(r >> 10);
  const float4* t4 = (const float4*)(te + r * 512);
  const float4* q4 = (const float4*)(qk + (size_t)b * 512);
  float4 a0 = t4[lane], a1 = t4[lane + 64];
  float4 c0 = q4[lane], c1 = q4[lane + 64];
  float s = a0.x * c0.x + a0.y * c0.y + a0.z * c0.z + a0.w * c0.w +
            a1.x * c1.x + a1.y * c1.y + a1.z * c1.z + a1.w * c1.w;
  s = wave_sum64(s);
  if (w16) {
    ushort4 h0 = make_ushort4(f2bf(a0.x), f2bf(a0.y), f2bf(a0.z), f2bf(a0.w));
    ushort4 h1 = make_ushort4(f2bf(a1.x), f2bf(a1.y), f2bf(a1.z), f2bf(a1.w));
    *(ushort4*)(te16 + r * 512 + lane * 4) = h0;
    *(ushort4*)(te16 + r * 512 + 256 + lane * 4) = h1;
  }
  if (lane == 0) logits[r] = s + constb[b] + x[r];
}

// ---------------- K4: softmax per batch; also init out = w + bd2 ----------------
__global__ __launch_bounds__(256) void softmax_kernel(
    const float* __restrict__ logits, const float* __restrict__ bd2,
    float* __restrict__ weight, float* __restrict__ out) {
  __shared__ float sm[4];
  const int b = blockIdx.x, tid = threadIdx.x;
  const int wave = tid >> 6, lane = tid & 63;
  float4 l4 = ((const float4*)(logits + (size_t)b * 1024))[tid];
  float m = fmaxf(fmaxf(l4.x, l4.y), fmaxf(l4.z, l4.w));
#pragma unroll
  for (int o = 32; o; o >>= 1) m = fmaxf(m, __shfl_xor(m, o, 64));
  if (lane == 0) sm[wave] = m;
  __syncthreads();
  float M = fmaxf(fmaxf(sm[0], sm[1]), fmaxf(sm[2], sm[3]));
  __syncthreads();
  float e0 = expf(l4.x - M), e1 = expf(l4.y - M), e2 = expf(l4.z - M), e3 = expf(l4.w - M);
  float ssum = wave_sum64(e0 + e1 + e2 + e3);
  if (lane == 0) sm[wave] = ssum;
  __syncthreads();
  float inv = 1.f / (sm[0] + sm[1] + sm[2] + sm[3]);
  float c = bd2[0];
  float4 w4 = make_float4(e0 * inv, e1 * inv, e2 * inv, e3 * inv);
  ((float4*)(weight + (size_t)b * 1024))[tid] = w4;
  ((float4*)(out + (size_t)b * 1024))[tid] = make_float4(w4.x + c, w4.y + c, w4.z + c, w4.w + c);
}

// ---------------- K5a: spart[(b,vq)][d] = sum_{v in chunk} w * te  (fp32 input) ----------------
__global__ __launch_bounds__(256) void wsum32_kernel(const float* __restrict__ te,
                                                     const float* __restrict__ weight,
                                                     float* __restrict__ spart) {
  __shared__ float wl[128];
  const int b = blockIdx.x >> 3, vq = blockIdx.x & 7;
  const int tid = threadIdx.x;
  if (tid < 128) wl[tid] = weight[(size_t)b * 1024 + vq * 128 + tid];
  __syncthreads();
  const float* tb = te + ((size_t)b * 1024 + (size_t)vq * 128) * 512;
  float s0 = 0.f, s1 = 0.f;
#pragma unroll 4
  for (int v = 0; v < 128; ++v) {
    float w = wl[v];
    s0 += w * tb[(size_t)v * 512 + tid];
    s1 += w * tb[(size_t)v * 512 + 256 + tid];
  }
  spart[(size_t)blockIdx.x * 512 + tid] = s0;
  spart[(size_t)blockIdx.x * 512 + 256 + tid] = s1;
}

// ---------------- K5a': same from bf16 te ----------------
__global__ __launch_bounds__(256) void wsum16_kernel(const unsigned short* __restrict__ te16,
                                                     const float* __restrict__ weight,
                                                     float* __restrict__ spart) {
  __shared__ float wl[128];
  __shared__ float red[4][512];
  const int b = blockIdx.x >> 3, vq = blockIdx.x & 7;
  const int tid = threadIdx.x;
  if (tid < 128) wl[tid] = weight[(size_t)b * 1024 + vq * 128 + tid];
  __syncthreads();
  const int g = tid & 63, vh = tid >> 6;
  const unsigned short* base =
      te16 + ((size_t)b * 1024 + vq * 128 + vh * 32) * 512 + g * 8;
  float acc[8] = {};
  for (int v = 0; v < 32; ++v) {
    float w = wl[vh * 32 + v];
    ushort8_t h = *(const ushort8_t*)(base + (size_t)v * 512);
#pragma unroll
    for (int i = 0; i < 8; ++i) acc[i] += w * bf2f(h[i]);
  }
#pragma unroll
  for (int i = 0; i < 8; ++i) red[vh][g * 8 + i] = acc[i];
  __syncthreads();
  for (int d = tid; d < 512; d += 256)
    spart[(size_t)blockIdx.x * 512 + d] =
        red[0][d] + red[1][d] + red[2][d] + red[3][d];
}

// ---------------- K6: decoder GEMM + fused epilogue (v8) ----------------
// 2048 blocks x 512 thr (8 waves = 2mh x 4nh). Block: 64 rows x 1024 cols, K=512.
// te16 -> LDS once (64KB, XOR swizzle, via global_load_lds w/ pre-swizzled src).
// W: 64 chunks of 16KB, LDS ring 4x16KB via global_load_lds, depth-3 counted
// vmcnt, ONE barrier per chunk. acc[2][2] in AGPR; arch-VGPR live set ~70.
#define GLD16(g, l)                                                              \
  __builtin_amdgcn_global_load_lds((const __attribute__((address_space(1))) void*)(g), \
                                   (__attribute__((address_space(3))) void*)(l), 16, 0, 0)

template <int USE16>
__global__ __launch_bounds__(512, 2) void decoder_kernel(
    const float* __restrict__ te, const unsigned short* __restrict__ te16,
    const unsigned short* __restrict__ wsW, const float* __restrict__ A,
    const float* __restrict__ Wd2, float* __restrict__ out) {
  extern __shared__ char lds[];   // te 65536 | W ring 4x16384  = 131072
  char* ring = lds + 65536;

  const int tid = threadIdx.x;
  const int wave = tid >> 6, lane = tid & 63;
  const int lhi = lane >> 4, llo = lane & 15;
  const int mh = wave >> 2, nh = wave & 3;
  const size_t row0 = (size_t)blockIdx.x * 64;
  const int b = (int)(blockIdx.x >> 4);

  // ---- W staging: chunk c -> ring slot (c&3); 2 GLD16 per thread ----
  auto stage = [&](int c) {
    const char* src = (const char*)wsW + (size_t)c * 16384 + wave * 1024 + lane * 16;
    char* dst = ring + (c & 3) * 16384 + wave * 1024;  // HW appends lane*16
    GLD16(src, dst);
    GLD16(src + 8192, dst + 8192);
  };

  // ---- prologue: stage te tile (64 rows x 1KB, swizzled) + first 3 W chunks ----
  if (USE16) {
    const char* src = (const char*)te16 + row0 * 1024;
#pragma unroll
    for (int it = 0; it < 8; ++it) {
      const int r = it * 8 + wave;  // r&7 == wave
      GLD16(src + (size_t)r * 1024 + ((lane * 16) ^ (wave << 4)), lds + r * 1024);
    }
    stage(0); stage(1); stage(2);
    asm volatile("s_waitcnt vmcnt(6)" ::: "memory");  // drain the 8 te loads only
  } else {
    const float* src = te + row0 * 512;
#pragma unroll
    for (int it = 0; it < 8; ++it) {
      int u = it * 512 + tid;  // 4096 16B-units
      int r = u >> 6, c = u & 63;
      const float4* s = (const float4*)(src + (size_t)r * 512 + c * 8);
      float4 f0 = s[0], f1 = s[1];
      ushort4 h0 = make_ushort4(f2bf(f0.x), f2bf(f0.y), f2bf(f0.z), f2bf(f0.w));
      ushort4 h1 = make_ushort4(f2bf(f1.x), f2bf(f1.y), f2bf(f1.z), f2bf(f1.w));
      char* d = lds + r * 1024 + ((c * 16) ^ ((r & 7) << 4));
      *(ushort4*)d = h0;
      *(ushort4*)(d + 8) = h1;
    }
    stage(0); stage(1); stage(2);
  }
  __syncthreads();

  // A-fragment byte offsets (row = mh*32 + m*16 + llo; add ks*128 per K-step)
  int aoffb[2][2];
#pragma unroll
  for (int m = 0; m < 2; ++m)
#pragma unroll
    for (int kc = 0; kc < 2; ++kc)
      aoffb[m][kc] = (mh * 32 + m * 16 + llo) * 1024 +
                     ((kc * 64 + lhi * 16) ^ ((llo & 7) << 4));

  const float* A_g = A + (size_t)b * 1024;
  fx4_t acc[2][2];
  const fx4_t zf = {0.f, 0.f, 0.f, 0.f};
  float pacc[2][4] = {};

#pragma unroll
  for (int nc = 0; nc < 8; ++nc) {
#pragma unroll
    for (int ks = 0; ks < 8; ++ks) {
      const int c = nc * 8 + ks;
      if (c <= 61)      asm volatile("s_waitcnt vmcnt(4)" ::: "memory");
      else if (c == 62) asm volatile("s_waitcnt vmcnt(2)" ::: "memory");
      else              asm volatile("s_waitcnt vmcnt(0)" ::: "memory");
      __builtin_amdgcn_s_barrier();
      __builtin_amdgcn_sched_barrier(0);
      if (ks == 0) { acc[0][0] = zf; acc[0][1] = zf; acc[1][0] = zf; acc[1][1] = zf; }
      const char* wb = ring + (c & 3) * 16384 + nh * 4096 + lane * 16;
      const char* tb = lds + ks * 128;
      bhalf8_t a00 = *(const bhalf8_t*)(tb + aoffb[0][0]);
      bhalf8_t a01 = *(const bhalf8_t*)(tb + aoffb[0][1]);
      bhalf8_t a10 = *(const bhalf8_t*)(tb + aoffb[1][0]);
      bhalf8_t a11 = *(const bhalf8_t*)(tb + aoffb[1][1]);
      bhalf8_t b00 = *(const bhalf8_t*)(wb);
      bhalf8_t b01 = *(const bhalf8_t*)(wb + 1024);
      bhalf8_t b10 = *(const bhalf8_t*)(wb + 2048);
      bhalf8_t b11 = *(const bhalf8_t*)(wb + 3072);
      acc[0][0] = __builtin_amdgcn_mfma_f32_16x16x32_bf16(a00, b00, acc[0][0], 0, 0, 0);
      acc[0][0] = __builtin_amdgcn_mfma_f32_16x16x32_bf16(a01, b01, acc[0][0], 0, 0, 0);
      acc[0][1] = __builtin_amdgcn_mfma_f32_16x16x32_bf16(a00, b10, acc[0][1], 0, 0, 0);
      acc[0][1] = __builtin_amdgcn_mfma_f32_16x16x32_bf16(a01, b11, acc[0][1], 0, 0, 0);
      acc[1][0] = __builtin_amdgcn_mfma_f32_16x16x32_bf16(a10, b00, acc[1][0], 0, 0, 0);
      acc[1][0] = __builtin_amdgcn_mfma_f32_16x16x32_bf16(a11, b01, acc[1][0], 0, 0, 0);
      acc[1][1] = __builtin_amdgcn_mfma_f32_16x16x32_bf16(a10, b10, acc[1][1], 0, 0, 0);
      acc[1][1] = __builtin_amdgcn_mfma_f32_16x16x32_bf16(a11, b11, acc[1][1], 0, 0, 0);
      if (c <= 60) stage(c + 3);
      if (ks == 7) {  // epilogue for this 128-col chunk (av/wv L2-hot scalar reads)
#pragma unroll
        for (int n = 0; n < 2; ++n) {
          const int j = nc * 128 + nh * 32 + n * 16 + llo;
          const float av = A_g[j];
          const float wvv = Wd2[j];
#pragma unroll
          for (int m = 0; m < 2; ++m)
#pragma unroll
            for (int rg = 0; rg < 4; ++rg)
              pacc[m][rg] += fmaxf(acc[m][n][rg] + av, 0.f) * wvv;
        }
      }
    }
  }

  // ---- reduction: ring area is drained & dead; reuse as red[4 nh][64 rows] ----
  __syncthreads();
  float* red = (float*)ring;
#pragma unroll
  for (int m = 0; m < 2; ++m)
#pragma unroll
    for (int rg = 0; rg < 4; ++rg) {
      float sv = pacc[m][rg];
      sv += __shfl_xor(sv, 1, 64);
      sv += __shfl_xor(sv, 2, 64);
      sv += __shfl_xor(sv, 4, 64);
      sv += __shfl_xor(sv, 8, 64);
      if (llo == 0) red[nh * 64 + mh * 32 + m * 16 + lhi * 4 + rg] = sv;
    }
  __syncthreads();
  if (tid < 64) {
    float s = red[tid] + red[64 + tid] + red[128 + tid] + red[192 + tid];
    out[row0 + tid] += s;  // out pre-initialized to w + bd2; rows exclusive per block
  }
}

// ---------------- launch ----------------
extern "C" void kernel_launch(void* const* d_in, const int* in_sizes, int n_in,
                              void* d_out, int out_size, void* d_ws, size_t ws_size,
                              hipStream_t stream) {
  const float* x = (const float*)d_in[0];
  const int* tsteps = (const int*)d_in[1];
  const float* qe = (const float*)d_in[2];
  const float* te = (const float*)d_in[3];
  const float* Wq = (const float*)d_in[4];
  const float* Wk = (const float*)d_in[5];
  const float* Wv = (const float*)d_in[6];
  const float* Wp = (const float*)d_in[7];
  const float* bp = (const float*)d_in[8];
  const float* Wt1 = (const float*)d_in[9];
  const float* bt1 = (const float*)d_in[10];
  const float* Wt2 = (const float*)d_in[11];
  const float* bt2 = (const float*)d_in[12];
  const float* Wd1 = (const float*)d_in[13];
  const float* bd1 = (const float*)d_in[14];
  const float* Wd2 = (const float*)d_in[15];
  const float* bd2 = (const float*)d_in[16];
  float* out = (float*)d_out;

  char* ws = (char*)d_ws;
  unsigned short* wsW = (unsigned short*)(ws + 0);     // 1 MB
  float* Wt1T = (float*)(ws + 1048576);                // 1 MB each
  float* Wt2T = (float*)(ws + 2097152);
  float* WqT = (float*)(ws + 3145728);
  float* WvT = (float*)(ws + 4194304);
  float* WpT = (float*)(ws + 5242880);
  float* Wd1aT = (float*)(ws + 6291456);               // 2 MB [512][1024]
  float* cond = (float*)(ws + 8388608);                // 256 KB each
  float* qk = (float*)(ws + 8650752);
  float* hbuf = (float*)(ws + 8912896);
  float* qbuf = (float*)(ws + 9175040);
  float* ubuf = (float*)(ws + 9437184);
  float* nebuf = (float*)(ws + 9699328);
  float* cb = (float*)(ws + 9961472);                  // 4 KB slot
  float* logits = (float*)(ws + 9965568);              // 512 KB
  float* wgt = (float*)(ws + 10489856);                // 512 KB
  float* spart = (float*)(ws + 11014144);              // 2 MB [128*8][512]
  float* Abuf = (float*)(ws + 13111296);               // 512 KB
  const size_t TE16_OFF = 14680064;                    // 14 MB
  const size_t TE16_BYTES = (size_t)128 * 1024 * 512 * 2;  // 128 MB
  unsigned short* te16 = (unsigned short*)(ws + TE16_OFF);
  const int use16 = (ws_size >= TE16_OFF + TE16_BYTES) ? 1 : 0;

  // weight transposes (coalesced mat-vec reads) + decoder W pre-pack
  transpose5_kernel<<<dim3(16, 16, 5), 256, 0, stream>>>(Wt1, Wt2, Wq, Wv, Wp,
                                                         Wt1T, Wt2T, WqT, WvT, WpT);
  transposed1_kernel<<<dim3(16, 32), 256, 0, stream>>>(Wd1, Wd1aT);
  convw_kernel<<<256, 256, 0, stream>>>(Wd1, wsW);

  // cond / q / qk chain (batched mat-vecs); constb fused into the qk pass
  hipMemsetAsync(cb, 0, 128 * sizeof(float), stream);
  gvec_kernel<0, 1, 0><<<dim3(128, 2), 256, 0, stream>>>(Wt1T, 512, nullptr, nullptr, bt1, tsteps, hbuf, nullptr);
  gvec_kernel<1, 0, 0><<<dim3(128, 2), 256, 0, stream>>>(Wt2T, 512, hbuf, nullptr, bt2, nullptr, cond, nullptr);
  gvec_kernel<2, 0, 0><<<dim3(128, 2), 256, 0, stream>>>(WqT, 512, qe, cond, nullptr, nullptr, qbuf, nullptr);
  gvec_kernel<1, 0, 1><<<dim3(128, 2), 256, 0, stream>>>(Wk, 512, qbuf, cond, nullptr, nullptr, qk, cb);

  logits_kernel<<<32768, 256, 0, stream>>>(te, qk, cb, x, logits, te16, use16);
  softmax_kernel<<<128, 256, 0, stream>>>(logits, bd2, wgt, out);
  if (use16)
    wsum16_kernel<<<1024, 256, 0, stream>>>(te16, wgt, spart);
  else
    wsum32_kernel<<<1024, 256, 0, stream>>>(te, wgt, spart);

  // new_emb -> A chain
  gvec_kernel<3, 0, 0><<<dim3(128, 2), 256, 0, stream>>>(WvT, 512, spart, cond, nullptr, nullptr, ubuf, nullptr);
  gvec_kernel<1, 0, 0><<<dim3(128, 2), 256, 0, stream>>>(WpT, 512, ubuf, nullptr, bp, nullptr, nebuf, nullptr);
  gvec_kernel<1, 0, 0><<<dim3(128, 4), 256, 0, stream>>>(Wd1aT, 1024, nebuf, nullptr, bd1, nullptr, Abuf, nullptr);

  if (use16) {
    (void)hipFuncSetAttribute((const void*)decoder_kernel<1>,
                              hipFuncAttributeMaxDynamicSharedMemorySize, 131072);
    decoder_kernel<1><<<2048, 512, 131072, stream>>>(te, te16, wsW, Abuf, Wd2, out);
  } else {
    (void)hipFuncSetAttribute((const void*)decoder_kernel<0>,
                              hipFuncAttributeMaxDynamicSharedMemorySize, 131072);
    decoder_kernel<0><<<2048, 512, 131072, stream>>>(te, te16, wsW, Abuf, Wd2, out);
  }
}